// Round 1
// baseline (10595.847 us; speedup 1.0000x reference)
//
#include <hip/hip_runtime.h>
#include <hip/hip_bf16.h>

#define BB 256   // batch
#define SS 512   // seq len
#define II 128   // input size
#define HH 256   // hidden size

typedef __attribute__((ext_vector_type(8))) __bf16 bf16x8;
typedef __attribute__((ext_vector_type(4))) float f32x4;

__device__ __forceinline__ unsigned short f2bf(float f) {
    unsigned u = __float_as_uint(f);
    unsigned r = u + 0x7fffu + ((u >> 16) & 1u);
    return (unsigned short)(r >> 16);
}

// ---------------------------------------------------------------------------
// Weight repack: fp32 [4H x K] (torch gate order i,f,g,o) -> bf16 MFMA-fragment
// order. Packed row p = nblk*16 + col encodes (slice s=p>>6, nw, nb, c) with
// gate = nb*2 + (c>>3), unit = s*16 + nw*8 + (c&7). Chunk q=(nblk*nkc+kc)*64+L
// holds lane L's 8 contiguous k elements -> B-frag load = 1 coalesced 16B read.
// ---------------------------------------------------------------------------
__global__ void pack_w_kernel(const float* __restrict__ Wih,
                              const float* __restrict__ Whh,
                              unsigned short* __restrict__ wp,
                              int Kin, int nkc) {
    int idx = blockIdx.x * blockDim.x + threadIdx.x;
    int total = 64 * nkc * 64;
    if (idx >= total) return;
    int nblk = idx / (nkc * 64);
    int rem  = idx % (nkc * 64);
    int kc = rem >> 6;
    int L  = rem & 63;
    int p  = nblk * 16 + (L & 15);
    int s  = p >> 6;
    int q6 = p & 63;
    int nw = q6 >> 5;
    int nb = (q6 >> 4) & 1;
    int c  = q6 & 15;
    int gam = nb * 2 + (c >> 3);            // 0:i 1:f 2:g 3:o
    int u   = s * 16 + nw * 8 + (c & 7);
    int srow = gam * HH + u;
    int k0 = kc * 32 + (L >> 4) * 8;
    unsigned short* dst = wp + (size_t)idx * 8;
    for (int j = 0; j < 8; ++j) {
        int k = k0 + j;
        float v = (k < Kin) ? Wih[(size_t)srow * Kin + k]
                            : Whh[(size_t)srow * HH + (k - Kin)];
        dst[j] = f2bf(v);
    }
}

__global__ void pack_bias_kernel(const float* bi0, const float* bh0,
                                 const float* bi1, const float* bh1,
                                 float* __restrict__ biasP) {
    int p = blockIdx.x * blockDim.x + threadIdx.x;
    if (p >= 2048) return;
    int layer = p >> 10;
    int pp = p & 1023;
    int s  = pp >> 6;
    int q6 = pp & 63;
    int nw = q6 >> 5;
    int nb = (q6 >> 4) & 1;
    int c  = q6 & 15;
    int gam = nb * 2 + (c >> 3);
    int u   = s * 16 + nw * 8 + (c & 7);
    int r = gam * HH + u;
    biasP[p] = layer ? (bi1[r] + bh1[r]) : (bi0[r] + bh0[r]);
}

__device__ __forceinline__ bool wait_flag(unsigned int* f) {
    long it = 0;
    while (__hip_atomic_load(f, __ATOMIC_RELAXED, __HIP_MEMORY_SCOPE_AGENT) < 16u) {
        __builtin_amdgcn_s_sleep(2);
        if (++it > 8000000l) return false;   // safety bailout: no hangs
    }
    return true;
}

// ---------------------------------------------------------------------------
// Persistent LSTM kernel. 256 WGs x 256 thr:
//   bid: layer = bid>>7, batch group g = (bid>>4)&7 (32 rows), slice s = bid&15
//        (16 hidden units -> 64 gate rows).
// Per step: stage A=[xt | h_{t-1}] (32 x Kc) bf16 into LDS, GEMM 32x64xKc via
// mfma_16x16x32_bf16 (wave w: mw=w&1 M-half, nwv=w>>1 unit-half), epilogue
// i/f/g/o via one shfl_xor(8), c-state in regs, h out via agent-scope stores,
// then flag increment. Layer1 waits on layer0's per-step flag (pipelined).
// ---------------------------------------------------------------------------
__global__ __launch_bounds__(256) void lstm_main(
    const float* __restrict__ x,
    const unsigned short* __restrict__ wp0,
    const unsigned short* __restrict__ wp1,
    const float* __restrict__ biasP,
    unsigned short* __restrict__ Y0,     // [S][B][H] bf16 layer-0 h
    unsigned int* __restrict__ flags,    // [2][S][8]
    float* __restrict__ out) {

    const int bid = blockIdx.x;
    const int layer = bid >> 7;
    const int g = (bid >> 4) & 7;
    const int s = bid & 15;
    const int tid = threadIdx.x;
    const int L = tid & 63;
    const int w = tid >> 6;
    const int mw = w & 1;
    const int nwv = w >> 1;
    const int c = L & 15;
    const int Kin = layer ? HH : II;
    const int Kc = Kin + HH;           // 512 / 384
    const int nkc = Kc >> 5;           // 16 / 12
    const int KcP = Kc + 8;            // pad: 2-way (free) LDS banking
    const int b0 = g * 32;

    __shared__ unsigned short As[32 * 520];
    __shared__ int abort_flag;
    if (tid == 0) abort_flag = 0;

    const unsigned short* wp = layer ? wp1 : wp0;
    const unsigned short* wB0 = wp + ((size_t)((s * 4 + nwv * 2 + 0) * nkc) * 64 + L) * 8;
    const unsigned short* wB1 = wp + ((size_t)((s * 4 + nwv * 2 + 1) * nkc) * 64 + L) * 8;
    const float bq0 = biasP[layer * 1024 + s * 64 + nwv * 32 + c];
    const float bq1 = biasP[layer * 1024 + s * 64 + nwv * 32 + 16 + c];

    float cst[4] = {0.f, 0.f, 0.f, 0.f};   // c-state, lanes c<8 authoritative

    unsigned int* fl0 = flags;
    unsigned int* fl1 = flags + SS * 8;
    float* outY = out;
    float* outHn = out + (size_t)BB * SS * HH;
    float* outCn = outHn + (size_t)BB * HH;
    unsigned int* Y0u = (unsigned int*)Y0;

    for (int t = 0; t < SS; ++t) {
        // ---- dependency wait (thread 0 spins, rest park at barrier) ----
        if (tid == 0) {
            bool ok = true;
            if (layer == 0) {
                if (t > 0) ok = wait_flag(fl0 + (t - 1) * 8 + g);
            } else {
                ok = wait_flag(fl0 + t * 8 + g);
                if (ok && t > 0) ok = wait_flag(fl1 + (t - 1) * 8 + g);
            }
            if (!ok) abort_flag = 1;
        }
        __syncthreads();
        if (abort_flag) return;

        // ---- stage A = [input | h_prev] into LDS (bf16) ----
        if (layer == 0) {
            // x part, cols [0,128): plain cached float4 loads
            for (int idx = tid; idx < 1024; idx += 256) {
                int row = idx >> 5, c4 = idx & 31;
                const float4 v = *(const float4*)(x + ((size_t)(b0 + row) * SS + t) * II + c4 * 4);
                ushort4 pk;
                pk.x = f2bf(v.x); pk.y = f2bf(v.y); pk.z = f2bf(v.z); pk.w = f2bf(v.w);
                *(ushort4*)&As[row * KcP + c4 * 4] = pk;
            }
            // h part, cols [128,384): agent-scope (coherent) loads of Y0[t-1]
            if (t > 0) {
                for (int idx = tid; idx < 4096; idx += 256) {
                    int row = idx >> 7, c2 = idx & 127;
                    unsigned v = __hip_atomic_load(
                        &Y0u[((size_t)(t - 1) * BB + b0 + row) * 128 + c2],
                        __ATOMIC_RELAXED, __HIP_MEMORY_SCOPE_AGENT);
                    *(unsigned*)&As[row * KcP + 128 + c2 * 2] = v;
                }
            } else {
                for (int idx = tid; idx < 4096; idx += 256) {
                    int row = idx >> 7, c2 = idx & 127;
                    *(unsigned*)&As[row * KcP + 128 + c2 * 2] = 0u;
                }
            }
        } else {
            // y0 part, cols [0,256): Y0[t]
            for (int idx = tid; idx < 4096; idx += 256) {
                int row = idx >> 7, c2 = idx & 127;
                unsigned v = __hip_atomic_load(
                    &Y0u[((size_t)t * BB + b0 + row) * 128 + c2],
                    __ATOMIC_RELAXED, __HIP_MEMORY_SCOPE_AGENT);
                *(unsigned*)&As[row * KcP + c2 * 2] = v;
            }
            // h part, cols [256,512): read back our own fp32 y output at t-1
            if (t > 0) {
                for (int idx = tid; idx < 8192; idx += 256) {
                    int row = idx >> 8, cc = idx & 255;
                    unsigned vb = __hip_atomic_load(
                        (unsigned*)&outY[((size_t)(b0 + row) * SS + (t - 1)) * HH + cc],
                        __ATOMIC_RELAXED, __HIP_MEMORY_SCOPE_AGENT);
                    As[row * KcP + 256 + cc] = f2bf(__uint_as_float(vb));
                }
            } else {
                for (int idx = tid; idx < 4096; idx += 256) {
                    int row = idx >> 7, c2 = idx & 127;
                    *(unsigned*)&As[row * KcP + 256 + c2 * 2] = 0u;
                }
            }
        }
        __syncthreads();

        // ---- GEMM: gates[32 x 64] += A[32 x Kc] * W^T ----
        f32x4 acc0 = {0.f, 0.f, 0.f, 0.f};
        f32x4 acc1 = {0.f, 0.f, 0.f, 0.f};
        const unsigned short* aBase = &As[(mw * 16 + c) * KcP + (L >> 4) * 8];
        for (int kc = 0; kc < nkc; ++kc) {
            bf16x8 a  = *(const bf16x8*)(aBase + kc * 32);
            bf16x8 b0f = *(const bf16x8*)(wB0 + (size_t)kc * 512);
            bf16x8 b1f = *(const bf16x8*)(wB1 + (size_t)kc * 512);
            acc0 = __builtin_amdgcn_mfma_f32_16x16x32_bf16(a, b0f, acc0, 0, 0, 0);
            acc1 = __builtin_amdgcn_mfma_f32_16x16x32_bf16(a, b1f, acc1, 0, 0, 0);
        }

        // ---- epilogue: acc0 = i|f, acc1 = g|o (partner lane L^8 has the rest)
        for (int r = 0; r < 4; ++r) {
            float x0 = acc0[r] + bq0;
            float x1 = acc1[r] + bq1;
            float y0v = __shfl_xor(x0, 8, 64);
            float y1v = __shfl_xor(x1, 8, 64);
            bool lo = (L & 8) == 0;
            float iv = lo ? x0 : y0v;
            float fv = lo ? y0v : x0;
            float gv = lo ? x1 : y1v;
            float ov = lo ? y1v : x1;
            iv = 1.f / (1.f + __expf(-iv));
            fv = 1.f / (1.f + __expf(-fv));
            ov = 1.f / (1.f + __expf(-ov));
            gv = 1.f - 2.f / (1.f + __expf(2.f * gv));
            float cn = fv * cst[r] + iv * gv;
            cst[r] = cn;
            float tc = 1.f - 2.f / (1.f + __expf(2.f * cn));
            float hn = ov * tc;
            if (lo) {
                int brow = b0 + mw * 16 + ((L >> 4) << 2) + r;
                int hu = s * 16 + nwv * 8 + (L & 7);
                if (layer == 0) {
                    __hip_atomic_store(&Y0[((size_t)t * BB + brow) * HH + hu], f2bf(hn),
                                       __ATOMIC_RELAXED, __HIP_MEMORY_SCOPE_AGENT);
                } else {
                    __hip_atomic_store((unsigned*)&outY[((size_t)brow * SS + t) * HH + hu],
                                       __float_as_uint(hn),
                                       __ATOMIC_RELAXED, __HIP_MEMORY_SCOPE_AGENT);
                    if (t == SS - 1) {
                        outHn[brow * HH + hu] = hn;
                        outCn[brow * HH + hu] = cn;
                    }
                }
            }
        }

        __syncthreads();  // all stores drained (barrier implies vmcnt(0))
        if (tid == 0) {
            __builtin_amdgcn_fence(__ATOMIC_RELEASE, "agent");
            atomicAdd((layer ? fl1 : fl0) + t * 8 + g, 1u);
        }
    }
}

extern "C" void kernel_launch(void* const* d_in, const int* in_sizes, int n_in,
                              void* d_out, int out_size, void* d_ws, size_t ws_size,
                              hipStream_t stream) {
    const float* x    = (const float*)d_in[0];
    const float* Wih0 = (const float*)d_in[1];
    const float* Whh0 = (const float*)d_in[2];
    const float* bih0 = (const float*)d_in[3];
    const float* bhh0 = (const float*)d_in[4];
    const float* Wih1 = (const float*)d_in[5];
    const float* Whh1 = (const float*)d_in[6];
    const float* bih1 = (const float*)d_in[7];
    const float* bhh1 = (const float*)d_in[8];

    char* ws = (char*)d_ws;
    size_t o = 0;
    unsigned short* wp0 = (unsigned short*)(ws + o); o += (size_t)64 * 12 * 512 * 2;  // 768 KB
    unsigned short* wp1 = (unsigned short*)(ws + o); o += (size_t)64 * 16 * 512 * 2;  // 1 MB
    float* biasP = (float*)(ws + o);                 o += 2048 * 4;
    unsigned short* Y0 = (unsigned short*)(ws + o);  o += (size_t)SS * BB * HH * 2;   // 67 MB
    unsigned int* flags = (unsigned int*)(ws + o);   o += (size_t)2 * SS * 8 * 4;     // 32 KB

    hipMemsetAsync(flags, 0, (size_t)2 * SS * 8 * 4, stream);
    pack_w_kernel<<<192, 256, 0, stream>>>(Wih0, Whh0, wp0, II, 12);
    pack_w_kernel<<<256, 256, 0, stream>>>(Wih1, Whh1, wp1, HH, 16);
    pack_bias_kernel<<<8, 256, 0, stream>>>(bih0, bhh0, bih1, bhh1, biasP);
    lstm_main<<<256, 256, 0, stream>>>(x, wp0, wp1, biasP, Y0, flags, (float*)d_out);
}

// Round 2
// 8841.163 us; speedup vs baseline: 1.1985x; 1.1985x over previous
//
#include <hip/hip_runtime.h>
#include <hip/hip_bf16.h>

#define BB 256   // batch
#define SS 512   // seq len
#define II 128   // input size
#define HH 256   // hidden size

typedef __attribute__((ext_vector_type(8))) __bf16 bf16x8;
typedef __attribute__((ext_vector_type(4))) float f32x4;

__device__ __forceinline__ unsigned short f2bf(float f) {
    unsigned u = __float_as_uint(f);
    unsigned r = u + 0x7fffu + ((u >> 16) & 1u);
    return (unsigned short)(r >> 16);
}

// ---------------------------------------------------------------------------
// Weight repack (unchanged from R1): fp32 [4H x K] -> bf16 MFMA B-fragment
// chains. Chain nblk = s*4 + nwv*2 + chain, chunk (nblk*nkc+kc)*64+L holds
// lane L's 8 contiguous k elems for frag (kc). Gate mapping per frag col c:
// chain0: c<8 -> i, c>=8 -> f ; chain1: c<8 -> g, c>=8 -> o ; unit=s*16+nwv*8+(c&7).
// ---------------------------------------------------------------------------
__global__ void pack_w_kernel(const float* __restrict__ Wih,
                              const float* __restrict__ Whh,
                              unsigned short* __restrict__ wp,
                              int Kin, int nkc) {
    int idx = blockIdx.x * blockDim.x + threadIdx.x;
    int total = 64 * nkc * 64;
    if (idx >= total) return;
    int nblk = idx / (nkc * 64);
    int rem  = idx % (nkc * 64);
    int kc = rem >> 6;
    int L  = rem & 63;
    int p  = nblk * 16 + (L & 15);
    int s  = p >> 6;
    int q6 = p & 63;
    int nw = q6 >> 5;
    int nb = (q6 >> 4) & 1;
    int c  = q6 & 15;
    int gam = nb * 2 + (c >> 3);            // 0:i 1:f 2:g 3:o
    int u   = s * 16 + nw * 8 + (c & 7);
    int srow = gam * HH + u;
    int k0 = kc * 32 + (L >> 4) * 8;
    unsigned short* dst = wp + (size_t)idx * 8;
    for (int j = 0; j < 8; ++j) {
        int k = k0 + j;
        float v = (k < Kin) ? Wih[(size_t)srow * Kin + k]
                            : Whh[(size_t)srow * HH + (k - Kin)];
        dst[j] = f2bf(v);
    }
}

__global__ void pack_bias_kernel(const float* bi0, const float* bh0,
                                 const float* bi1, const float* bh1,
                                 float* __restrict__ biasP) {
    int p = blockIdx.x * blockDim.x + threadIdx.x;
    if (p >= 2048) return;
    int layer = p >> 10;
    int pp = p & 1023;
    int s  = pp >> 6;
    int q6 = pp & 63;
    int nw = q6 >> 5;
    int nb = (q6 >> 4) & 1;
    int c  = q6 & 15;
    int gam = nb * 2 + (c >> 3);
    int u   = s * 16 + nw * 8 + (c & 7);
    int r = gam * HH + u;
    biasP[p] = layer ? (bi1[r] + bh1[r]) : (bi0[r] + bh0[r]);
}

__device__ __forceinline__ bool wait_flag(unsigned int* f) {
    long it = 0;
    while (__hip_atomic_load(f, __ATOMIC_RELAXED, __HIP_MEMORY_SCOPE_AGENT) < 16u) {
        __builtin_amdgcn_s_sleep(1);
        if (++it > 2000000l) return false;   // safety bailout: no hangs
    }
    return true;
}

// ---------------------------------------------------------------------------
// Persistent 2-layer LSTM. 256 WGs x 256 thr, 1 WG/CU.
//   bid<128: layer0, bid>=128: layer1. g=(bid>>4)&7 (32 batch rows), s=bid&15
//   (16 hidden units -> 64 gate cols as 2 MFMA B-chains).
// R2 changes vs R1:
//   - full weight slice preloaded into VGPRs once (96/128 regs) -> K-loop is
//     pure LDS-read + MFMA, no global weight traffic.
//   - staging loads batched & vectorized (float4/uint4), issued in one
//     latency window; x prefetched before the flag wait.
//   - plain vector loads for no-reuse buffers (x, Y0) under agent acquire
//     fence; depth-4 bf16 ring Y1r for layer-1 h (dword agent atomics, slot
//     reuse makes plain loads stale-cache-unsafe).
// ---------------------------------------------------------------------------
template <int LAYER>
__device__ __forceinline__ void run_layer(
    int bid, const float* __restrict__ x,
    const unsigned short* __restrict__ wp,
    const float* __restrict__ biasP,
    unsigned short* __restrict__ Y0,
    unsigned short* __restrict__ Y1,
    unsigned int* __restrict__ flags,
    float* __restrict__ out,
    unsigned short* As, int* abort_flag) {

    constexpr int KIN = LAYER ? HH : II;
    constexpr int KC  = KIN + HH;        // 384 / 512
    constexpr int NKC = KC >> 5;         // 12 / 16
    constexpr int KCP = KC + 8;          // +8 shorts: A-frag row stride ≡ 4 banks

    const int g = (bid >> 4) & 7;
    const int s = bid & 15;
    const int tid = threadIdx.x;
    const int L = tid & 63;
    const int w = tid >> 6;
    const int mw = w & 1;
    const int nwv = w >> 1;
    const int c = L & 15;
    const int b0 = g * 32;

    // ---- persistent weight fragments in VGPRs ----
    const unsigned short* wB0 = wp + ((size_t)((s * 4 + nwv * 2 + 0) * NKC) * 64 + L) * 8;
    const unsigned short* wB1 = wp + ((size_t)((s * 4 + nwv * 2 + 1) * NKC) * 64 + L) * 8;
    bf16x8 w0r[NKC], w1r[NKC];
#pragma unroll
    for (int kc = 0; kc < NKC; ++kc) {
        w0r[kc] = *(const bf16x8*)(wB0 + (size_t)kc * 512);
        w1r[kc] = *(const bf16x8*)(wB1 + (size_t)kc * 512);
    }
    const float bq0 = biasP[LAYER * 1024 + s * 64 + nwv * 32 + c];
    const float bq1 = biasP[LAYER * 1024 + s * 64 + nwv * 32 + 16 + c];

    float cst[4] = {0.f, 0.f, 0.f, 0.f};

    unsigned int* fl0 = flags;
    unsigned int* fl1 = flags + SS * 8;
    float* outY  = out;
    float* outHn = out + (size_t)BB * SS * HH;
    float* outCn = outHn + (size_t)BB * HH;
    const uint4* Y0q = (const uint4*)Y0;          // 32 uint4 per 256-unit row
    unsigned int* Y1u = (unsigned int*)Y1;        // 128 dwords per row

    // per-thread staging geometry
    const int rowb = tid >> 5;        // uint4 chunks: row = rowb + 8k, col = cc
    const int cc   = tid & 31;
    const int rowd = tid >> 7;        // dword chunks: row = rowd + 2k, col = cc2
    const int cc2  = tid & 127;

    for (int t = 0; t < SS; ++t) {
        // ---- prefetch x (layer0 only; no dependency) ----
        float4 xv[4];
        if (LAYER == 0) {
#pragma unroll
            for (int k = 0; k < 4; ++k) {
                int row = rowb + 8 * k;
                xv[k] = *(const float4*)(x + ((size_t)(b0 + row) * SS + t) * II + cc * 4);
            }
        }

        // ---- dependency wait ----
        if (tid == 0) {
            bool ok = true;
            if (LAYER == 0) {
                if (t > 0) ok = wait_flag(fl0 + (t - 1) * 8 + g);
            } else {
                ok = wait_flag(fl0 + t * 8 + g);
                if (ok && t > 0) ok = wait_flag(fl1 + (t - 1) * 8 + g);
            }
            if (!ok) *abort_flag = 1;
        }
        __syncthreads();
        if (*abort_flag) return;
        __builtin_amdgcn_fence(__ATOMIC_ACQUIRE, "agent");

        // ---- stage A = [input | h_prev] into LDS, loads batched ----
        if (LAYER == 0) {
            uint4 hv[4];
            if (t > 0) {
#pragma unroll
                for (int k = 0; k < 4; ++k) {
                    int row = rowb + 8 * k;
                    hv[k] = Y0q[((size_t)(t - 1) * BB + b0 + row) * 32 + cc];
                }
            } else {
#pragma unroll
                for (int k = 0; k < 4; ++k) hv[k] = make_uint4(0, 0, 0, 0);
            }
#pragma unroll
            for (int k = 0; k < 4; ++k) {
                int row = rowb + 8 * k;
                ushort4 pk;
                pk.x = f2bf(xv[k].x); pk.y = f2bf(xv[k].y);
                pk.z = f2bf(xv[k].z); pk.w = f2bf(xv[k].w);
                *(ushort4*)&As[row * KCP + cc * 4] = pk;
                *(uint4*)&As[row * KCP + 128 + cc * 8] = hv[k];
            }
        } else {
            uint4 yv[4];
            unsigned hv[16];
#pragma unroll
            for (int k = 0; k < 4; ++k) {
                int row = rowb + 8 * k;
                yv[k] = Y0q[((size_t)t * BB + b0 + row) * 32 + cc];
            }
            if (t > 0) {
                const unsigned int* src = Y1u + ((size_t)((t - 1) & 3) * BB + b0) * 128;
#pragma unroll
                for (int k = 0; k < 16; ++k) {
                    int row = rowd + 2 * k;
                    hv[k] = __hip_atomic_load(src + (size_t)row * 128 + cc2,
                                              __ATOMIC_RELAXED, __HIP_MEMORY_SCOPE_AGENT);
                }
            } else {
#pragma unroll
                for (int k = 0; k < 16; ++k) hv[k] = 0u;
            }
#pragma unroll
            for (int k = 0; k < 4; ++k) {
                int row = rowb + 8 * k;
                *(uint4*)&As[row * KCP + cc * 8] = yv[k];
            }
#pragma unroll
            for (int k = 0; k < 16; ++k) {
                int row = rowd + 2 * k;
                *(unsigned*)&As[row * KCP + 256 + cc2 * 2] = hv[k];
            }
        }
        __syncthreads();

        // ---- GEMM: gates[32 x 64] = A[32 x KC] * W^T (weights in regs) ----
        f32x4 acc0 = {0.f, 0.f, 0.f, 0.f};
        f32x4 acc1 = {0.f, 0.f, 0.f, 0.f};
        const unsigned short* aBase = &As[(mw * 16 + c) * KCP + (L >> 4) * 8];
#pragma unroll
        for (int kc = 0; kc < NKC; ++kc) {
            bf16x8 a = *(const bf16x8*)(aBase + kc * 32);
            acc0 = __builtin_amdgcn_mfma_f32_16x16x32_bf16(a, w0r[kc], acc0, 0, 0, 0);
            acc1 = __builtin_amdgcn_mfma_f32_16x16x32_bf16(a, w1r[kc], acc1, 0, 0, 0);
        }

        // ---- epilogue: acc0 = i|f, acc1 = g|o (partner lane L^8) ----
#pragma unroll
        for (int r = 0; r < 4; ++r) {
            float x0 = acc0[r] + bq0;
            float x1 = acc1[r] + bq1;
            float y0v = __shfl_xor(x0, 8, 64);
            float y1v = __shfl_xor(x1, 8, 64);
            bool lo = (L & 8) == 0;
            float iv = lo ? x0 : y0v;
            float fv = lo ? y0v : x0;
            float gv = lo ? x1 : y1v;
            float ov = lo ? y1v : x1;
            iv = 1.f / (1.f + __expf(-iv));
            fv = 1.f / (1.f + __expf(-fv));
            ov = 1.f / (1.f + __expf(-ov));
            gv = 1.f - 2.f / (1.f + __expf(2.f * gv));
            float cn = fv * cst[r] + iv * gv;
            cst[r] = cn;
            float tc = 1.f - 2.f / (1.f + __expf(2.f * cn));
            float hn = ov * tc;
            if (lo) {
                int brow = b0 + mw * 16 + ((L >> 4) << 2) + r;
                int hu = s * 16 + nwv * 8 + (L & 7);
                if (LAYER == 0) {
                    __hip_atomic_store(&Y0[((size_t)t * BB + brow) * HH + hu], f2bf(hn),
                                       __ATOMIC_RELAXED, __HIP_MEMORY_SCOPE_AGENT);
                } else {
                    __hip_atomic_store(&Y1[((size_t)(t & 3) * BB + brow) * HH + hu], f2bf(hn),
                                       __ATOMIC_RELAXED, __HIP_MEMORY_SCOPE_AGENT);
                    outY[((size_t)brow * SS + t) * HH + hu] = hn;
                    if (t == SS - 1) {
                        outHn[brow * HH + hu] = hn;
                        outCn[brow * HH + hu] = cn;
                    }
                }
            }
        }

        __syncthreads();  // drains stores (barrier implies vmcnt(0))
        if (tid == 0) {
            __builtin_amdgcn_fence(__ATOMIC_RELEASE, "agent");
            atomicAdd((LAYER ? fl1 : fl0) + t * 8 + g, 1u);
        }
    }
}

__global__ __launch_bounds__(256, 1) void lstm_main(
    const float* __restrict__ x,
    const unsigned short* __restrict__ wp0,
    const unsigned short* __restrict__ wp1,
    const float* __restrict__ biasP,
    unsigned short* __restrict__ Y0,
    unsigned short* __restrict__ Y1,
    unsigned int* __restrict__ flags,
    float* __restrict__ out) {

    __shared__ unsigned short As[32 * 520];
    __shared__ int abort_flag;
    if (threadIdx.x == 0) abort_flag = 0;

    int bid = blockIdx.x;
    if (bid < 128)
        run_layer<0>(bid, x, wp0, biasP, Y0, Y1, flags, out, As, &abort_flag);
    else
        run_layer<1>(bid, x, wp1, biasP, Y0, Y1, flags, out, As, &abort_flag);
}

extern "C" void kernel_launch(void* const* d_in, const int* in_sizes, int n_in,
                              void* d_out, int out_size, void* d_ws, size_t ws_size,
                              hipStream_t stream) {
    const float* x    = (const float*)d_in[0];
    const float* Wih0 = (const float*)d_in[1];
    const float* Whh0 = (const float*)d_in[2];
    const float* bih0 = (const float*)d_in[3];
    const float* bhh0 = (const float*)d_in[4];
    const float* Wih1 = (const float*)d_in[5];
    const float* Whh1 = (const float*)d_in[6];
    const float* bih1 = (const float*)d_in[7];
    const float* bhh1 = (const float*)d_in[8];

    char* ws = (char*)d_ws;
    size_t o = 0;
    unsigned short* wp0 = (unsigned short*)(ws + o); o += (size_t)64 * 12 * 512 * 2;  // 768 KB
    unsigned short* wp1 = (unsigned short*)(ws + o); o += (size_t)64 * 16 * 512 * 2;  // 1 MB
    float* biasP = (float*)(ws + o);                 o += 2048 * 4;
    unsigned short* Y0 = (unsigned short*)(ws + o);  o += (size_t)SS * BB * HH * 2;   // 67 MB
    unsigned short* Y1 = (unsigned short*)(ws + o);  o += (size_t)4 * BB * HH * 2;    // 512 KB
    unsigned int* flags = (unsigned int*)(ws + o);   o += (size_t)2 * SS * 8 * 4;     // 32 KB

    hipMemsetAsync(flags, 0, (size_t)2 * SS * 8 * 4, stream);
    pack_w_kernel<<<192, 256, 0, stream>>>(Wih0, Whh0, wp0, II, 12);
    pack_w_kernel<<<256, 256, 0, stream>>>(Wih1, Whh1, wp1, HH, 16);
    pack_bias_kernel<<<8, 256, 0, stream>>>(bih0, bhh0, bih1, bhh1, biasP);
    lstm_main<<<256, 256, 0, stream>>>(x, wp0, wp1, biasP, Y0, Y1, flags, (float*)d_out);
}

// Round 4
// 6162.896 us; speedup vs baseline: 1.7193x; 1.4346x over previous
//
#include <hip/hip_runtime.h>
#include <hip/hip_bf16.h>

#define BB 256   // batch
#define SS 512   // seq len
#define II 128   // input size
#define HH 256   // hidden size

typedef __attribute__((ext_vector_type(8))) __bf16 bf16x8;
typedef __attribute__((ext_vector_type(4))) float f32x4;

__device__ __forceinline__ unsigned short f2bf(float f) {
    unsigned u = __float_as_uint(f);
    unsigned r = u + 0x7fffu + ((u >> 16) & 1u);
    return (unsigned short)(r >> 16);
}

// ---------------------------------------------------------------------------
// Weight repack (unchanged): fp32 [4H x K] -> bf16 MFMA B-fragment chains.
// Chain nblk = s*4 + nwv*2 + chain; chunk (nblk*nkc+kc)*64+L holds lane L's
// 8 contiguous k elems. Gate map per frag col c: chain0 c<8->i, c>=8->f;
// chain1 c<8->g, c>=8->o; unit = s*16 + nwv*8 + (c&7).
// ---------------------------------------------------------------------------
__global__ void pack_w_kernel(const float* __restrict__ Wih,
                              const float* __restrict__ Whh,
                              unsigned short* __restrict__ wp,
                              int Kin, int nkc) {
    int idx = blockIdx.x * blockDim.x + threadIdx.x;
    int total = 64 * nkc * 64;
    if (idx >= total) return;
    int nblk = idx / (nkc * 64);
    int rem  = idx % (nkc * 64);
    int kc = rem >> 6;
    int L  = rem & 63;
    int p  = nblk * 16 + (L & 15);
    int s  = p >> 6;
    int q6 = p & 63;
    int nw = q6 >> 5;
    int nb = (q6 >> 4) & 1;
    int c  = q6 & 15;
    int gam = nb * 2 + (c >> 3);            // 0:i 1:f 2:g 3:o
    int u   = s * 16 + nw * 8 + (c & 7);
    int srow = gam * HH + u;
    int k0 = kc * 32 + (L >> 4) * 8;
    unsigned short* dst = wp + (size_t)idx * 8;
    for (int j = 0; j < 8; ++j) {
        int k = k0 + j;
        float v = (k < Kin) ? Wih[(size_t)srow * Kin + k]
                            : Whh[(size_t)srow * HH + (k - Kin)];
        dst[j] = f2bf(v);
    }
}

__global__ void pack_bias_kernel(const float* bi0, const float* bh0,
                                 const float* bi1, const float* bh1,
                                 float* __restrict__ biasP) {
    int p = blockIdx.x * blockDim.x + threadIdx.x;
    if (p >= 2048) return;
    int layer = p >> 10;
    int pp = p & 1023;
    int s  = pp >> 6;
    int q6 = pp & 63;
    int nw = q6 >> 5;
    int nb = (q6 >> 4) & 1;
    int c  = q6 & 15;
    int gam = nb * 2 + (c >> 3);
    int u   = s * 16 + nw * 8 + (c & 7);
    int r = gam * HH + u;
    biasP[p] = layer ? (bi1[r] + bh1[r]) : (bi0[r] + bh0[r]);
}

__device__ __forceinline__ bool wait_flag(unsigned int* f) {
    long it = 0;
    while (__hip_atomic_load(f, __ATOMIC_RELAXED, __HIP_MEMORY_SCOPE_AGENT) < 16u) {
        __builtin_amdgcn_s_sleep(1);
        if (++it > 2000000l) return false;   // safety bailout: no hangs
    }
    return true;
}

// ---------------------------------------------------------------------------
// Persistent 2-layer LSTM. 256 WGs x 256 thr, 1 WG/CU.
// Coherence protocol (R1-evidence-backed):
//   - producer: relaxed agent atomic stores for cross-WG data, then
//     __syncthreads (vmcnt drain) + fence(release,agent) [buffer_wbl2 -> data
//     at LLC] + relaxed flag atomicAdd.  REQUIRED: without the release fence
//     (R3) sparse stale reads appear (absmax 1.9e-2) -> relaxed sc-bit stores
//     are NOT LLC-visible at vmcnt retire.
//   - consumer: relaxed agent atomic loads only, NO acquire fence (R1 proved
//     correct; R2's acquire buffer_inv caused the 1.45 GB writeback storm).
//   - x/weights/bias normal cached loads; outY plain cached stores.
// ---------------------------------------------------------------------------
template <int LAYER>
__device__ __forceinline__ void run_layer(
    int bid, const float* __restrict__ x,
    const unsigned short* __restrict__ wp,
    const float* __restrict__ biasP,
    unsigned short* __restrict__ Y0,
    unsigned short* __restrict__ Y1,
    unsigned int* __restrict__ flags,
    float* __restrict__ out,
    unsigned short* As, int* abort_flag) {

    constexpr int KIN = LAYER ? HH : II;
    constexpr int KC  = KIN + HH;        // 384 / 512
    constexpr int NKC = KC >> 5;         // 12 / 16
    constexpr int KCP = KC + 8;          // A-row stride offset: 8 shorts

    const int g = (bid >> 4) & 7;
    const int s = bid & 15;
    const int tid = threadIdx.x;
    const int L = tid & 63;
    const int w = tid >> 6;
    const int mw = w & 1;
    const int nwv = w >> 1;
    const int c = L & 15;
    const int b0 = g * 32;

    // ---- persistent weight fragments (VGPR/AGPR file) ----
    const unsigned short* wB0 = wp + ((size_t)((s * 4 + nwv * 2 + 0) * NKC) * 64 + L) * 8;
    const unsigned short* wB1 = wp + ((size_t)((s * 4 + nwv * 2 + 1) * NKC) * 64 + L) * 8;
    bf16x8 w0r[NKC], w1r[NKC];
#pragma unroll
    for (int kc = 0; kc < NKC; ++kc) {
        w0r[kc] = *(const bf16x8*)(wB0 + (size_t)kc * 512);
        w1r[kc] = *(const bf16x8*)(wB1 + (size_t)kc * 512);
    }
    const float bq0 = biasP[LAYER * 1024 + s * 64 + nwv * 32 + c];
    const float bq1 = biasP[LAYER * 1024 + s * 64 + nwv * 32 + 16 + c];

    float cst[4] = {0.f, 0.f, 0.f, 0.f};

    unsigned int* fl0 = flags;
    unsigned int* fl1 = flags + SS * 8;
    float* outY  = out;
    float* outHn = out + (size_t)BB * SS * HH;
    float* outCn = outHn + (size_t)BB * HH;
    unsigned long long* Y0l = (unsigned long long*)Y0;   // 64 u64 per 256-unit row
    unsigned long long* Y1l = (unsigned long long*)Y1;
    unsigned int* Y0u = (unsigned int*)Y0;
    unsigned int* Y1u = (unsigned int*)Y1;

    // staging geometry: one batch row per 8 threads, 8 x u64 per thread
    const int row8 = tid >> 3;        // 0..31
    const int c8   = tid & 7;         // u64 col base; cols c8 + 8j, j=0..7
    // x staging (layer0): float4 rows rowb+8k, col cc
    const int rowb = tid >> 5;
    const int cc   = tid & 31;

    int ahead0 = 0;                   // layer1: fl0 peek-ahead cache (flags monotone)

    for (int t = 0; t < SS; ++t) {
        unsigned long long yv[8];     // layer1: y0[t] staged regs
        float4 xv[4];                 // layer0: x[t]

        if (LAYER == 0) {
            // ---- prefetch x (no dependency) ----
#pragma unroll
            for (int k = 0; k < 4; ++k) {
                int row = rowb + 8 * k;
                xv[k] = *(const float4*)(x + ((size_t)(b0 + row) * SS + t) * II + cc * 4);
            }
            if (tid == 0 && t > 0) {
                if (!wait_flag(fl0 + (t - 1) * 8 + g)) *abort_flag = 1;
            }
            __syncthreads();
            if (*abort_flag) return;
        } else {
            // ---- gate on fl0[t] (usually pre-satisfied; peek-ahead) ----
            if (tid == 0 && t >= ahead0) {
                if (!wait_flag(fl0 + t * 8 + g)) *abort_flag = 1;
                int pt = t + 16; if (pt > SS - 1) pt = SS - 1;
                if (__hip_atomic_load(fl0 + pt * 8 + g, __ATOMIC_RELAXED,
                                      __HIP_MEMORY_SCOPE_AGENT) >= 16u)
                    ahead0 = pt + 1;
            }
            __syncthreads();
            if (*abort_flag) return;
            // ---- issue y0[t] loads; latency overlaps the fl1 poll ----
            {
                unsigned long long* sp = Y0l + ((size_t)t * BB + b0 + row8) * 64;
#pragma unroll
                for (int j = 0; j < 8; ++j)
                    yv[j] = __hip_atomic_load(sp + c8 + 8 * j, __ATOMIC_RELAXED,
                                              __HIP_MEMORY_SCOPE_AGENT);
            }
            if (tid == 0 && t > 0) {
                if (!wait_flag(fl1 + (t - 1) * 8 + g)) *abort_flag = 1;
            }
            __syncthreads();
            if (*abort_flag) return;
        }

        // ---- h_{t-1} gather (batched u64 agent atomics) ----
        unsigned long long hv[8];
        if (t > 0) {
            unsigned long long* sp = (LAYER == 0)
                ? Y0l + ((size_t)(t - 1) * BB + b0 + row8) * 64
                : Y1l + ((size_t)((t - 1) & 3) * BB + b0 + row8) * 64;
#pragma unroll
            for (int j = 0; j < 8; ++j)
                hv[j] = __hip_atomic_load(sp + c8 + 8 * j, __ATOMIC_RELAXED,
                                          __HIP_MEMORY_SCOPE_AGENT);
        } else {
#pragma unroll
            for (int j = 0; j < 8; ++j) hv[j] = 0ull;
        }

        // ---- write A = [input | h_prev] to LDS ----
        if (LAYER == 0) {
#pragma unroll
            for (int k = 0; k < 4; ++k) {
                int row = rowb + 8 * k;
                ushort4 pk;
                pk.x = f2bf(xv[k].x); pk.y = f2bf(xv[k].y);
                pk.z = f2bf(xv[k].z); pk.w = f2bf(xv[k].w);
                *(ushort4*)&As[row * KCP + cc * 4] = pk;
            }
        } else {
#pragma unroll
            for (int j = 0; j < 8; ++j)
                *(unsigned long long*)&As[row8 * KCP + (c8 + 8 * j) * 4] = yv[j];
        }
#pragma unroll
        for (int j = 0; j < 8; ++j)
            *(unsigned long long*)&As[row8 * KCP + KIN + (c8 + 8 * j) * 4] = hv[j];
        __syncthreads();

        // ---- GEMM: gates[32 x 64] = A[32 x KC] * W^T ----
        f32x4 acc0 = {0.f, 0.f, 0.f, 0.f};
        f32x4 acc1 = {0.f, 0.f, 0.f, 0.f};
        const unsigned short* aBase = &As[(mw * 16 + c) * KCP + (L >> 4) * 8];
#pragma unroll
        for (int kc = 0; kc < NKC; ++kc) {
            bf16x8 a = *(const bf16x8*)(aBase + kc * 32);
            acc0 = __builtin_amdgcn_mfma_f32_16x16x32_bf16(a, w0r[kc], acc0, 0, 0, 0);
            acc1 = __builtin_amdgcn_mfma_f32_16x16x32_bf16(a, w1r[kc], acc1, 0, 0, 0);
        }

        // ---- epilogue: acc0 = i|f, acc1 = g|o (partner lane L^8) ----
#pragma unroll
        for (int r = 0; r < 4; ++r) {
            float x0 = acc0[r] + bq0;
            float x1 = acc1[r] + bq1;
            float y0v = __shfl_xor(x0, 8, 64);
            float y1v = __shfl_xor(x1, 8, 64);
            bool lo = (L & 8) == 0;
            float iv = lo ? x0 : y0v;
            float fv = lo ? y0v : x0;
            float gv = lo ? x1 : y1v;
            float ov = lo ? y1v : x1;
            iv = 1.f / (1.f + __expf(-iv));
            fv = 1.f / (1.f + __expf(-fv));
            ov = 1.f / (1.f + __expf(-ov));
            gv = 1.f - 2.f / (1.f + __expf(2.f * gv));
            float cn = fv * cst[r] + iv * gv;
            cst[r] = cn;
            float tc = 1.f - 2.f / (1.f + __expf(2.f * cn));
            float hn = ov * tc;

            int brow = b0 + mw * 16 + ((L >> 4) << 2) + r;
            int hu = s * 16 + nwv * 8 + (L & 7);
            // pack 2 adjacent units (lane pair L, L^1) into one 4B atomic store
            unsigned hb = (unsigned)f2bf(hn);
            unsigned pb = (unsigned)__shfl_xor((int)hb, 1, 64);
            unsigned packed = hb | (pb << 16);
            if (lo && (L & 1) == 0) {
                size_t di = (((size_t)(LAYER == 0 ? t * BB : (size_t)(t & 3) * BB)
                              + brow) * HH + hu) >> 1;
                __hip_atomic_store((LAYER == 0 ? Y0u : Y1u) + di, packed,
                                   __ATOMIC_RELAXED, __HIP_MEMORY_SCOPE_AGENT);
            }
            if (LAYER == 1 && lo) {
                outY[((size_t)brow * SS + t) * HH + hu] = hn;
                if (t == SS - 1) {
                    outHn[brow * HH + hu] = hn;
                    outCn[brow * HH + hu] = cn;
                }
            }
        }

        __syncthreads();  // drains all stores (vmcnt(0)) before publish
        if (tid == 0) {
            // REQUIRED (R3 failure): buffer_wbl2 pushes the relaxed atomic
            // stores to the LLC before the flag RMW lands there.
            __builtin_amdgcn_fence(__ATOMIC_RELEASE, "agent");
            atomicAdd((LAYER ? fl1 : fl0) + t * 8 + g, 1u);
        }
    }
}

__global__ __launch_bounds__(256, 1) void lstm_main(
    const float* __restrict__ x,
    const unsigned short* __restrict__ wp0,
    const unsigned short* __restrict__ wp1,
    const float* __restrict__ biasP,
    unsigned short* __restrict__ Y0,
    unsigned short* __restrict__ Y1,
    unsigned int* __restrict__ flags,
    float* __restrict__ out) {

    __shared__ unsigned short As[32 * 520];
    __shared__ int abort_flag;
    if (threadIdx.x == 0) abort_flag = 0;

    int bid = blockIdx.x;
    if (bid < 128)
        run_layer<0>(bid, x, wp0, biasP, Y0, Y1, flags, out, As, &abort_flag);
    else
        run_layer<1>(bid, x, wp1, biasP, Y0, Y1, flags, out, As, &abort_flag);
}

extern "C" void kernel_launch(void* const* d_in, const int* in_sizes, int n_in,
                              void* d_out, int out_size, void* d_ws, size_t ws_size,
                              hipStream_t stream) {
    const float* x    = (const float*)d_in[0];
    const float* Wih0 = (const float*)d_in[1];
    const float* Whh0 = (const float*)d_in[2];
    const float* bih0 = (const float*)d_in[3];
    const float* bhh0 = (const float*)d_in[4];
    const float* Wih1 = (const float*)d_in[5];
    const float* Whh1 = (const float*)d_in[6];
    const float* bih1 = (const float*)d_in[7];
    const float* bhh1 = (const float*)d_in[8];

    char* ws = (char*)d_ws;
    size_t o = 0;
    unsigned short* wp0 = (unsigned short*)(ws + o); o += (size_t)64 * 12 * 512 * 2;  // 768 KB
    unsigned short* wp1 = (unsigned short*)(ws + o); o += (size_t)64 * 16 * 512 * 2;  // 1 MB
    float* biasP = (float*)(ws + o);                 o += 2048 * 4;
    unsigned short* Y0 = (unsigned short*)(ws + o);  o += (size_t)SS * BB * HH * 2;   // 67 MB
    unsigned short* Y1 = (unsigned short*)(ws + o);  o += (size_t)4 * BB * HH * 2;    // 512 KB
    unsigned int* flags = (unsigned int*)(ws + o);   o += (size_t)2 * SS * 8 * 4;     // 32 KB

    hipMemsetAsync(flags, 0, (size_t)2 * SS * 8 * 4, stream);
    pack_w_kernel<<<192, 256, 0, stream>>>(Wih0, Whh0, wp0, II, 12);
    pack_w_kernel<<<256, 256, 0, stream>>>(Wih1, Whh1, wp1, HH, 16);
    pack_bias_kernel<<<8, 256, 0, stream>>>(bih0, bhh0, bih1, bhh1, biasP);
    lstm_main<<<256, 256, 0, stream>>>(x, wp0, wp1, biasP, Y0, Y1, flags, (float*)d_out);
}